// Round 1
// baseline (8724.756 us; speedup 1.0000x reference)
//
#include <hip/hip_runtime.h>
#include <math.h>

// Problem constants
#define B_  4
#define S_  2048
#define D_  768
#define H_  12
#define DK_ 64
#define M_  (B_ * S_)   // 8192 rows for projection GEMMs

// ---------------- Projection GEMM: out = X @ W^T + bias ----------------
// X: (M_, D_) row-major.  W: (D_, D_) row-major as (out_features, in_features).
// mode 0: scatter output to (B,H,S,DK) layout.  mode 1: plain (M_, D_).
#define BM 128
#define BN 128
#define BK 16

__global__ __launch_bounds__(256) void proj_kernel(
    const float* __restrict__ X, const float* __restrict__ W,
    const float* __restrict__ bias, float* __restrict__ out, const int mode)
{
    // Transposed tiles: Xt[k][m], Wt[k][n] so fragment reads are float4 (b128).
    __shared__ __align__(16) float Xt[BK][BM + 4];
    __shared__ __align__(16) float Wt[BK][BN + 4];

    const int t  = threadIdx.x;
    const int tx = t & 15;      // col group 0..15
    const int ty = t >> 4;      // row group 0..15
    const int m0 = blockIdx.x * BM;
    const int n0 = blockIdx.y * BN;

    float acc[8][8];
#pragma unroll
    for (int i = 0; i < 8; i++)
#pragma unroll
        for (int j = 0; j < 8; j++) acc[i][j] = 0.f;

    for (int k0 = 0; k0 < D_; k0 += BK) {
        // Stage 128x16 tiles of X and W, transposed into LDS. 512 float4 each.
#pragma unroll
        for (int i = 0; i < 2; i++) {
            int v   = t + i * 256;
            int row = v >> 2;     // 0..127
            int c4  = v & 3;      // 0..3 (k in steps of 4)
            float4 xv = *(const float4*)(X + (size_t)(m0 + row) * D_ + k0 + c4 * 4);
            Xt[c4*4+0][row] = xv.x; Xt[c4*4+1][row] = xv.y;
            Xt[c4*4+2][row] = xv.z; Xt[c4*4+3][row] = xv.w;
            float4 wv = *(const float4*)(W + (size_t)(n0 + row) * D_ + k0 + c4 * 4);
            Wt[c4*4+0][row] = wv.x; Wt[c4*4+1][row] = wv.y;
            Wt[c4*4+2][row] = wv.z; Wt[c4*4+3][row] = wv.w;
        }
        __syncthreads();

#pragma unroll
        for (int kk = 0; kk < BK; kk++) {
            // rows: ty*4..+3 and 64+ty*4..+3 ; cols: tx*4..+3 and 64+tx*4..+3
            float4 a0 = *(const float4*)&Xt[kk][ty * 4];
            float4 a1 = *(const float4*)&Xt[kk][64 + ty * 4];
            float4 b0 = *(const float4*)&Wt[kk][tx * 4];
            float4 b1 = *(const float4*)&Wt[kk][64 + tx * 4];
            float a[8]  = {a0.x, a0.y, a0.z, a0.w, a1.x, a1.y, a1.z, a1.w};
            float bb[8] = {b0.x, b0.y, b0.z, b0.w, b1.x, b1.y, b1.z, b1.w};
#pragma unroll
            for (int i = 0; i < 8; i++)
#pragma unroll
                for (int j = 0; j < 8; j++) acc[i][j] += a[i] * bb[j];
        }
        __syncthreads();
    }

    // Epilogue: add bias, write float4 per 4-col group.
#pragma unroll
    for (int i = 0; i < 8; i++) {
        int r = (i < 4) ? (ty * 4 + i) : (64 + ty * 4 + (i - 4));
        int m = m0 + r;
#pragma unroll
        for (int jh = 0; jh < 2; jh++) {
            int n = n0 + jh * 64 + tx * 4;
            float4 o;
            o.x = acc[i][jh*4+0] + bias[n+0];
            o.y = acc[i][jh*4+1] + bias[n+1];
            o.z = acc[i][jh*4+2] + bias[n+2];
            o.w = acc[i][jh*4+3] + bias[n+3];
            size_t idx;
            if (mode == 0) {
                int b  = m >> 11;        // m / S_
                int s  = m & (S_ - 1);
                int h  = n >> 6;         // n / DK_
                int dk = n & 63;
                idx = ((size_t)(b * H_ + h) * S_ + s) * DK_ + dk;
            } else {
                idx = (size_t)m * D_ + n;
            }
            *(float4*)(out + idx) = o;
        }
    }
}

// ---------------- Flash attention (fp32, online softmax) ----------------
// Q,K,V: (B*H, S, DK). mask: (B,S) int. O: (B,S,D) with heads merged.
// One block = one (b,h, 64-row q-tile). 256 threads; thread owns 4 q-rows x
// 4 cols (keys in score phase, dims in PV phase). Row stats reduced across
// the 16 lanes sharing a row group via shfl_xor (same wave by construction).
__global__ __launch_bounds__(256) void attn_kernel(
    const float* __restrict__ Q, const float* __restrict__ K,
    const float* __restrict__ V, const int* __restrict__ mask,
    float* __restrict__ O)
{
    __shared__ __align__(16) float Qt[DK_][68];   // Qt[d][r]
    __shared__ __align__(16) float KVt[64][68];   // K^T [d][j], then V [j][d]
    __shared__ __align__(16) float Pt[64][68];    // Pt[j][r]

    const int t  = threadIdx.x;
    const int tx = t & 15;
    const int ty = t >> 4;
    const int qt = blockIdx.x & 31;   // S_/64 = 32 q-tiles
    const int bh = blockIdx.x >> 5;
    const int b  = bh / H_;
    const int h  = bh % H_;
    const int q0 = qt * 64;

    // Load Q tile transposed: Qt[d][r]
    const float* Qbase = Q + ((size_t)bh * S_ + q0) * DK_;
#pragma unroll
    for (int i = 0; i < 4; i++) {
        int v   = t + i * 256;
        int row = v >> 4;    // 0..63
        int c4  = v & 15;    // 0..15
        float4 qv = *(const float4*)(Qbase + (size_t)row * DK_ + c4 * 4);
        Qt[c4*4+0][row] = qv.x; Qt[c4*4+1][row] = qv.y;
        Qt[c4*4+2][row] = qv.z; Qt[c4*4+3][row] = qv.w;
    }

    float m_i[4], l_i[4], acc[4][4];
#pragma unroll
    for (int i = 0; i < 4; i++) {
        m_i[i] = -INFINITY;
        l_i[i] = 0.f;
#pragma unroll
        for (int j = 0; j < 4; j++) acc[i][j] = 0.f;
    }

    const float* Kbase = K + (size_t)bh * S_ * DK_;
    const float* Vbase = V + (size_t)bh * S_ * DK_;
    const int*   mbase = mask + (size_t)b * S_;

    __syncthreads();

    for (int j0 = 0; j0 < S_; j0 += 64) {
        // ---- stage K^T into KVt: KVt[d][j] ----
#pragma unroll
        for (int i = 0; i < 4; i++) {
            int v   = t + i * 256;
            int row = v >> 4;
            int c4  = v & 15;
            float4 kv = *(const float4*)(Kbase + (size_t)(j0 + row) * DK_ + c4 * 4);
            KVt[c4*4+0][row] = kv.x; KVt[c4*4+1][row] = kv.y;
            KVt[c4*4+2][row] = kv.z; KVt[c4*4+3][row] = kv.w;
        }
        __syncthreads();

        // ---- scores: s[i][j] = q(row 4ty+i) . k(col 4tx+j) ----
        float s[4][4];
#pragma unroll
        for (int i = 0; i < 4; i++)
#pragma unroll
            for (int j = 0; j < 4; j++) s[i][j] = 0.f;

#pragma unroll
        for (int d = 0; d < DK_; d++) {
            float4 a  = *(const float4*)&Qt[d][ty * 4];
            float4 kk = *(const float4*)&KVt[d][tx * 4];
            float av[4] = {a.x, a.y, a.z, a.w};
            float kv[4] = {kk.x, kk.y, kk.z, kk.w};
#pragma unroll
            for (int i = 0; i < 4; i++)
#pragma unroll
                for (int j = 0; j < 4; j++) s[i][j] += av[i] * kv[j];
        }
        __syncthreads();   // everyone done reading K^T

        // ---- scale then mask to exactly -1e9 (matches reference order) ----
        int4 mv = *(const int4*)(mbase + j0 + tx * 4);
        int mm[4] = {mv.x, mv.y, mv.z, mv.w};
#pragma unroll
        for (int j = 0; j < 4; j++) {
            if (mm[j] == 0) {
#pragma unroll
                for (int i = 0; i < 4; i++) s[i][j] = -1e9f;
            } else {
#pragma unroll
                for (int i = 0; i < 4; i++) s[i][j] *= 0.125f;  // 1/sqrt(64)
            }
        }

        // ---- stage V into KVt (direct [j][d]) — overlaps softmax below ----
#pragma unroll
        for (int i = 0; i < 4; i++) {
            int v   = t + i * 256;
            int row = v >> 4;
            int c4  = v & 15;
            float4 vv = *(const float4*)(Vbase + (size_t)(j0 + row) * DK_ + c4 * 4);
            *(float4*)&KVt[row][c4 * 4] = vv;
        }

        // ---- online softmax (rows live in one wave; reduce over 16 lanes) ----
        float p[4][4];
#pragma unroll
        for (int i = 0; i < 4; i++) {
            float rm = fmaxf(fmaxf(s[i][0], s[i][1]), fmaxf(s[i][2], s[i][3]));
            rm = fmaxf(rm, __shfl_xor(rm, 1));
            rm = fmaxf(rm, __shfl_xor(rm, 2));
            rm = fmaxf(rm, __shfl_xor(rm, 4));
            rm = fmaxf(rm, __shfl_xor(rm, 8));
            float mn = fmaxf(m_i[i], rm);           // mn >= -1e9 > -inf always
            float sc = __expf(m_i[i] - mn);         // first iter: exp(-inf)=0
            float rs = 0.f;
#pragma unroll
            for (int j = 0; j < 4; j++) { p[i][j] = __expf(s[i][j] - mn); rs += p[i][j]; }
            rs += __shfl_xor(rs, 1);
            rs += __shfl_xor(rs, 2);
            rs += __shfl_xor(rs, 4);
            rs += __shfl_xor(rs, 8);
            l_i[i] = l_i[i] * sc + rs;
            m_i[i] = mn;
#pragma unroll
            for (int j = 0; j < 4; j++) acc[i][j] *= sc;
        }

        // ---- write P transposed: Pt[j][r] ----
#pragma unroll
        for (int j = 0; j < 4; j++) {
            float4 pv = make_float4(p[0][j], p[1][j], p[2][j], p[3][j]);
            *(float4*)&Pt[tx * 4 + j][ty * 4] = pv;
        }
        __syncthreads();   // V staged + Pt visible

        // ---- PV: acc[i][jj] += sum_j P[r][j] * V[j][dd] ----
#pragma unroll
        for (int j = 0; j < 64; j++) {
            float4 a  = *(const float4*)&Pt[j][ty * 4];
            float4 vv = *(const float4*)&KVt[j][tx * 4];
            float av[4]  = {a.x, a.y, a.z, a.w};
            float vvv[4] = {vv.x, vv.y, vv.z, vv.w};
#pragma unroll
            for (int i = 0; i < 4; i++)
#pragma unroll
                for (int jj = 0; jj < 4; jj++) acc[i][jj] += av[i] * vvv[jj];
        }
        __syncthreads();   // done reading Pt/KVt before next tile overwrites
    }

    // ---- epilogue: normalize and write merged-head layout (B,S,D) ----
    float* Obase = O + ((size_t)b * S_ + q0) * D_ + h * DK_;
#pragma unroll
    for (int i = 0; i < 4; i++) {
        float inv = 1.f / l_i[i];
        float4 o;
        o.x = acc[i][0] * inv; o.y = acc[i][1] * inv;
        o.z = acc[i][2] * inv; o.w = acc[i][3] * inv;
        *(float4*)(Obase + (size_t)(ty * 4 + i) * D_ + tx * 4) = o;
    }
}

// ---------------- host launcher ----------------
extern "C" void kernel_launch(void* const* d_in, const int* in_sizes, int n_in,
                              void* d_out, int out_size, void* d_ws, size_t ws_size,
                              hipStream_t stream) {
    (void)in_sizes; (void)n_in; (void)out_size; (void)ws_size;

    const float* query = (const float*)d_in[0];
    const float* key_  = (const float*)d_in[1];
    const float* value = (const float*)d_in[2];
    const int*   mask  = (const int*)d_in[3];
    const float* Wq = (const float*)d_in[4];  const float* bq = (const float*)d_in[5];
    const float* Wk = (const float*)d_in[6];  const float* bk = (const float*)d_in[7];
    const float* Wv = (const float*)d_in[8];  const float* bv = (const float*)d_in[9];
    const float* Wo = (const float*)d_in[10]; const float* bo = (const float*)d_in[11];
    float* out = (float*)d_out;

    // Workspace: Q,K,V in (B,H,S,DK) + merged-head attention output (B,S,D).
    float* Qb = (float*)d_ws;
    float* Kb = Qb + (size_t)M_ * D_;
    float* Vb = Kb + (size_t)M_ * D_;
    float* Xb = Vb + (size_t)M_ * D_;

    dim3 gproj(M_ / BM, D_ / BN);   // 64 x 6
    proj_kernel<<<gproj, 256, 0, stream>>>(query, Wq, bq, Qb, 0);
    proj_kernel<<<gproj, 256, 0, stream>>>(key_,  Wk, bk, Kb, 0);
    proj_kernel<<<gproj, 256, 0, stream>>>(value, Wv, bv, Vb, 0);

    attn_kernel<<<dim3(B_ * H_ * (S_ / 64)), 256, 0, stream>>>(Qb, Kb, Vb, mask, Xb);

    proj_kernel<<<gproj, 256, 0, stream>>>(Xb, Wo, bo, out, 1);
}

// Round 2
// 890.958 us; speedup vs baseline: 9.7926x; 9.7926x over previous
//
#include <hip/hip_runtime.h>
#include <math.h>

// Problem constants
#define B_  4
#define S_  2048
#define D_  768
#define H_  12
#define DK_ 64
#define M_  (B_ * S_)   // 8192 rows for projection GEMMs

typedef float f32x4 __attribute__((ext_vector_type(4)));
typedef __bf16 bf16x8 __attribute__((ext_vector_type(8)));
typedef short s16x8 __attribute__((ext_vector_type(8)));

// fp32 -> bf16 round-to-nearest-even
static __device__ __forceinline__ unsigned short f2bf(float f) {
    unsigned u = __builtin_bit_cast(unsigned, f);
    u += 0x7fffu + ((u >> 16) & 1u);
    return (unsigned short)(u >> 16);
}

// ---------------- Projection GEMM: out = X @ W^T + bias ----------------
// X: (M_, D_) row-major fp32.  W: (D_, D_) fp32 (out_features, in_features).
// mode 0: bf16 out, (B,H,S,DK) layout   (Q, K)
// mode 1: fp32 out, plain (M_, D_)      (final output)
// mode 2: bf16 out, V^T (B,H,DK,S)      (V)
#define BM 128
#define BN 128
#define BK 16

__global__ __launch_bounds__(256) void proj_kernel(
    const float* __restrict__ X, const float* __restrict__ W,
    const float* __restrict__ bias, void* __restrict__ outp, const int mode)
{
    __shared__ __align__(16) float Xt[BK][BM + 4];
    __shared__ __align__(16) float Wt[BK][BN + 4];

    const int t  = threadIdx.x;
    const int tx = t & 15;
    const int ty = t >> 4;
    const int m0 = blockIdx.x * BM;
    const int n0 = blockIdx.y * BN;

    float acc[8][8];
#pragma unroll
    for (int i = 0; i < 8; i++)
#pragma unroll
        for (int j = 0; j < 8; j++) acc[i][j] = 0.f;

    for (int k0 = 0; k0 < D_; k0 += BK) {
#pragma unroll
        for (int i = 0; i < 2; i++) {
            int v   = t + i * 256;
            int row = v >> 2;
            int c4  = v & 3;
            float4 xv = *(const float4*)(X + (size_t)(m0 + row) * D_ + k0 + c4 * 4);
            Xt[c4*4+0][row] = xv.x; Xt[c4*4+1][row] = xv.y;
            Xt[c4*4+2][row] = xv.z; Xt[c4*4+3][row] = xv.w;
            float4 wv = *(const float4*)(W + (size_t)(n0 + row) * D_ + k0 + c4 * 4);
            Wt[c4*4+0][row] = wv.x; Wt[c4*4+1][row] = wv.y;
            Wt[c4*4+2][row] = wv.z; Wt[c4*4+3][row] = wv.w;
        }
        __syncthreads();

#pragma unroll
        for (int kk = 0; kk < BK; kk++) {
            float4 a0 = *(const float4*)&Xt[kk][ty * 4];
            float4 a1 = *(const float4*)&Xt[kk][64 + ty * 4];
            float4 b0 = *(const float4*)&Wt[kk][tx * 4];
            float4 b1 = *(const float4*)&Wt[kk][64 + tx * 4];
            float a[8]  = {a0.x, a0.y, a0.z, a0.w, a1.x, a1.y, a1.z, a1.w};
            float bb[8] = {b0.x, b0.y, b0.z, b0.w, b1.x, b1.y, b1.z, b1.w};
#pragma unroll
            for (int i = 0; i < 8; i++)
#pragma unroll
                for (int j = 0; j < 8; j++) acc[i][j] += a[i] * bb[j];
        }
        __syncthreads();
    }

    if (mode == 1) {
        float* out = (float*)outp;
#pragma unroll
        for (int i = 0; i < 8; i++) {
            int m = m0 + ((i < 4) ? (ty * 4 + i) : (64 + ty * 4 + (i - 4)));
#pragma unroll
            for (int jh = 0; jh < 2; jh++) {
                int n = n0 + jh * 64 + tx * 4;
                float4 o;
                o.x = acc[i][jh*4+0] + bias[n+0];
                o.y = acc[i][jh*4+1] + bias[n+1];
                o.z = acc[i][jh*4+2] + bias[n+2];
                o.w = acc[i][jh*4+3] + bias[n+3];
                *(float4*)(out + (size_t)m * D_ + n) = o;
            }
        }
    } else if (mode == 0) {
        unsigned short* out = (unsigned short*)outp;
#pragma unroll
        for (int i = 0; i < 8; i++) {
            int m = m0 + ((i < 4) ? (ty * 4 + i) : (64 + ty * 4 + (i - 4)));
            int b = m >> 11;
            int s = m & (S_ - 1);
#pragma unroll
            for (int jh = 0; jh < 2; jh++) {
                int n  = n0 + jh * 64 + tx * 4;
                int h  = n >> 6;
                int dk = n & 63;
                ushort4 o;
                o.x = f2bf(acc[i][jh*4+0] + bias[n+0]);
                o.y = f2bf(acc[i][jh*4+1] + bias[n+1]);
                o.z = f2bf(acc[i][jh*4+2] + bias[n+2]);
                o.w = f2bf(acc[i][jh*4+3] + bias[n+3]);
                *(ushort4*)(out + ((size_t)(b * H_ + h) * S_ + s) * DK_ + dk) = o;
            }
        }
    } else {
        // mode 2: V^T bf16 (B,H,DK,S) — pack 4 consecutive s-rows per store
        unsigned short* out = (unsigned short*)outp;
#pragma unroll
        for (int grp = 0; grp < 2; grp++) {
            int mrow = m0 + grp * 64 + ty * 4;   // 4 consecutive rows
            int b = mrow >> 11;
            int s = mrow & (S_ - 1);
#pragma unroll
            for (int j = 0; j < 8; j++) {
                int n  = n0 + (j >> 2) * 64 + tx * 4 + (j & 3);
                int h  = n >> 6;
                int dk = n & 63;
                float bv = bias[n];
                ushort4 o;
                o.x = f2bf(acc[grp*4+0][j] + bv);
                o.y = f2bf(acc[grp*4+1][j] + bv);
                o.z = f2bf(acc[grp*4+2][j] + bv);
                o.w = f2bf(acc[grp*4+3][j] + bv);
                *(ushort4*)(out + ((size_t)(b * H_ + h) * DK_ + dk) * S_ + s) = o;
            }
        }
    }
}

// ---------------- MFMA flash attention (bf16 inputs, fp32 accum) ----------
// Qb,Kb: (B*H, S, DK) bf16.  VTb: (B*H, DK, S) bf16.  mask: (B,S) int.
// O: (B, S, D) fp32, heads merged.
// Block = 256 threads = 4 independent waves; wave owns 16 q-rows. No
// __syncthreads. K/V fragments read straight from global (L2-resident:
// 512 KB per head). P transposed through a 2 KB/wave XOR-swizzled LDS buf.
//
// MFMA 16x16x32 layouts (guide-verified):
//   A: lane supplies A[m=l&15][k=8*(l>>4)+e]
//   B: lane supplies B[k=8*(l>>4)+e][n=l&15]
//   C/D: lane holds D[m=4*(l>>4)+j][n=l&15], j=0..3
__global__ __launch_bounds__(256) void attn_mfma(
    const unsigned short* __restrict__ Qb, const unsigned short* __restrict__ Kb,
    const unsigned short* __restrict__ VTb, const int* __restrict__ mask,
    float* __restrict__ O)
{
    __shared__ unsigned short Pt[4][1024];   // 16x64 bf16 per wave, swizzled

    const int t  = threadIdx.x;
    const int w  = t >> 6;
    const int l  = t & 63;
    const int lr = l & 15;
    const int lg = l >> 4;

    const int qt = blockIdx.x & 31;       // 32 q-tiles of 64
    const int bh = blockIdx.x >> 5;
    const int b  = bh / H_;
    const int h  = bh - b * H_;
    const int q0 = qt * 64 + w * 16;      // this wave's q-row base

    // Q fragments, held in registers for all 32 K-tiles
    const unsigned short* qp = Qb + ((size_t)bh * S_ + q0 + lr) * DK_ + lg * 8;
    bf16x8 aQ0 = *(const bf16x8*)(qp);
    bf16x8 aQ1 = *(const bf16x8*)(qp + 32);

    f32x4 acc_o[4];
    float m_i[4], l_i[4];
#pragma unroll
    for (int j = 0; j < 4; j++) {
        acc_o[j] = (f32x4){0.f, 0.f, 0.f, 0.f};
        m_i[j] = -INFINITY;
        l_i[j] = 0.f;
    }

    const unsigned short* kbase = Kb + (size_t)bh * S_ * DK_;
    const unsigned short* vbase = VTb + (size_t)bh * DK_ * S_;
    const int* mbase = mask + b * S_;
    unsigned short* pt = &Pt[w][0];

    for (int j0 = 0; j0 < S_; j0 += 64) {
        // ---- K fragments: key rows nf*16+lr, k-cols 8*lg.. (16B each) ----
        bf16x8 bK[4][2];
#pragma unroll
        for (int nf = 0; nf < 4; nf++) {
            const unsigned short* kp = kbase + (size_t)(j0 + nf * 16 + lr) * DK_ + lg * 8;
            bK[nf][0] = *(const bf16x8*)(kp);
            bK[nf][1] = *(const bf16x8*)(kp + 32);
        }
        int mv[4];
#pragma unroll
        for (int nf = 0; nf < 4; nf++) mv[nf] = mbase[j0 + nf * 16 + lr];

        // ---- QK^T: S[m][key] ----
        f32x4 sc4[4];
#pragma unroll
        for (int nf = 0; nf < 4; nf++) {
            f32x4 z = (f32x4){0.f, 0.f, 0.f, 0.f};
            z = __builtin_amdgcn_mfma_f32_16x16x32_bf16(aQ0, bK[nf][0], z, 0, 0, 0);
            z = __builtin_amdgcn_mfma_f32_16x16x32_bf16(aQ1, bK[nf][1], z, 0, 0, 0);
            sc4[nf] = z;
        }

        // ---- V fragments (issue early; consumed after softmax) ----
        bf16x8 bV[4][2];
#pragma unroll
        for (int nd = 0; nd < 4; nd++) {
            const unsigned short* vp = vbase + (size_t)(nd * 16 + lr) * S_ + j0 + lg * 8;
            bV[nd][0] = *(const bf16x8*)(vp);
            bV[nd][1] = *(const bf16x8*)(vp + 32);
        }

        // ---- scale then mask to exactly -1e9 (reference order) ----
        float s[4][4];
#pragma unroll
        for (int nf = 0; nf < 4; nf++) {
            bool msk = (mv[nf] == 0);
#pragma unroll
            for (int j = 0; j < 4; j++)
                s[nf][j] = msk ? -1e9f : sc4[nf][j] * 0.125f;
        }

        // ---- online softmax (row j lives in 16 lanes sharing lg) ----
        float pr[4][4], scale_j[4];
#pragma unroll
        for (int j = 0; j < 4; j++) {
            float rm = fmaxf(fmaxf(s[0][j], s[1][j]), fmaxf(s[2][j], s[3][j]));
            rm = fmaxf(rm, __shfl_xor(rm, 1));
            rm = fmaxf(rm, __shfl_xor(rm, 2));
            rm = fmaxf(rm, __shfl_xor(rm, 4));
            rm = fmaxf(rm, __shfl_xor(rm, 8));
            float mn = fmaxf(m_i[j], rm);
            float sc = __expf(m_i[j] - mn);   // first iter: exp(-inf)=0
            float rs = 0.f;
#pragma unroll
            for (int nf = 0; nf < 4; nf++) { pr[nf][j] = __expf(s[nf][j] - mn); rs += pr[nf][j]; }
            rs += __shfl_xor(rs, 1);
            rs += __shfl_xor(rs, 2);
            rs += __shfl_xor(rs, 4);
            rs += __shfl_xor(rs, 8);
            l_i[j] = l_i[j] * sc + rs;
            m_i[j] = mn;
            scale_j[j] = sc;
        }

        // ---- rescale O accumulator ----
#pragma unroll
        for (int nd = 0; nd < 4; nd++)
#pragma unroll
            for (int j = 0; j < 4; j++) acc_o[nd][j] *= scale_j[j];

        // ---- P -> swizzled LDS (bf16), then read back as A-fragments ----
#pragma unroll
        for (int nf = 0; nf < 4; nf++)
#pragma unroll
            for (int j = 0; j < 4; j++) {
                int m = lg * 4 + j;
                int n = nf * 16 + lr;
                pt[(m * 64 + n) ^ ((m & 7) << 3)] = f2bf(pr[nf][j]);
            }
        int i0 = (lr * 64 + lg * 8) ^ ((lr & 7) << 3);
        int i1 = (lr * 64 + 32 + lg * 8) ^ ((lr & 7) << 3);
        bf16x8 aP0 = *(const bf16x8*)&pt[i0];
        bf16x8 aP1 = *(const bf16x8*)&pt[i1];

        // ---- PV: O[m][d] += P[m][key] V[key][d] ----
#pragma unroll
        for (int nd = 0; nd < 4; nd++) {
            acc_o[nd] = __builtin_amdgcn_mfma_f32_16x16x32_bf16(aP0, bV[nd][0], acc_o[nd], 0, 0, 0);
            acc_o[nd] = __builtin_amdgcn_mfma_f32_16x16x32_bf16(aP1, bV[nd][1], acc_o[nd], 0, 0, 0);
        }
    }

    // ---- epilogue: normalize, write merged-head fp32 (B,S,D) ----
    float* ob = O + ((size_t)b * S_ + q0) * D_ + h * DK_;
#pragma unroll
    for (int j = 0; j < 4; j++) {
        float inv = 1.f / l_i[j];
        int m = lg * 4 + j;
#pragma unroll
        for (int nd = 0; nd < 4; nd++)
            ob[(size_t)m * D_ + nd * 16 + lr] = acc_o[nd][j] * inv;
    }
}

// ---------------- host launcher ----------------
extern "C" void kernel_launch(void* const* d_in, const int* in_sizes, int n_in,
                              void* d_out, int out_size, void* d_ws, size_t ws_size,
                              hipStream_t stream) {
    (void)in_sizes; (void)n_in; (void)out_size; (void)ws_size;

    const float* query = (const float*)d_in[0];
    const float* key_  = (const float*)d_in[1];
    const float* value = (const float*)d_in[2];
    const int*   mask  = (const int*)d_in[3];
    const float* Wq = (const float*)d_in[4];  const float* bq = (const float*)d_in[5];
    const float* Wk = (const float*)d_in[6];  const float* bk = (const float*)d_in[7];
    const float* Wv = (const float*)d_in[8];  const float* bv = (const float*)d_in[9];
    const float* Wo = (const float*)d_in[10]; const float* bo = (const float*)d_in[11];
    float* out = (float*)d_out;

    // Workspace: Qb,Kb (B,H,S,DK) bf16; VT (B,H,DK,S) bf16; Xb (B,S,D) fp32.
    unsigned short* Qb = (unsigned short*)d_ws;
    unsigned short* Kb = Qb + (size_t)M_ * D_;
    unsigned short* VT = Kb + (size_t)M_ * D_;
    float*          Xb = (float*)(VT + (size_t)M_ * D_);

    dim3 gproj(M_ / BM, D_ / BN);   // 64 x 6
    proj_kernel<<<gproj, 256, 0, stream>>>(query, Wq, bq, Qb, 0);
    proj_kernel<<<gproj, 256, 0, stream>>>(key_,  Wk, bk, Kb, 0);
    proj_kernel<<<gproj, 256, 0, stream>>>(value, Wv, bv, VT, 2);

    attn_mfma<<<dim3(B_ * H_ * (S_ / 64)), 256, 0, stream>>>(Qb, Kb, VT, mask, Xb);

    proj_kernel<<<gproj, 256, 0, stream>>>(Xb, Wo, bo, (void*)out, 1);
}

// Round 3
// 472.462 us; speedup vs baseline: 18.4666x; 1.8858x over previous
//
#include <hip/hip_runtime.h>
#include <math.h>

// Problem constants
#define B_  4
#define S_  2048
#define D_  768
#define H_  12
#define DK_ 64
#define M_  (B_ * S_)   // 8192 rows for projection GEMMs

typedef float f32x4 __attribute__((ext_vector_type(4)));
typedef __bf16 bf16x8 __attribute__((ext_vector_type(8)));

// fp32 -> bf16 round-to-nearest-even
static __device__ __forceinline__ unsigned short f2bf(float f) {
    unsigned u = __builtin_bit_cast(unsigned, f);
    u += 0x7fffu + ((u >> 16) & 1u);
    return (unsigned short)(u >> 16);
}

// ---------------- MFMA projection GEMM: out = X @ W^T + bias --------------
// X: (M_, D_) fp32.  W: (D_, D_) fp32 (out_features, in_features).
// Convert-on-stage: fp32 global -> bf16 LDS (XOR slot-swizzled, 2-way free).
// mode 0: bf16 out, (B,H,S,DK) layout   (Q, K)
// mode 1: fp32 out, plain (M_, D_)      (final output)
// mode 2: bf16 out, V^T (B,H,DK,S)      (V)
//
// MFMA 16x16x32 layouts (guide-verified):
//   A: lane supplies A[m=l&15][k=8*(l>>4)+e]
//   B: lane supplies B[k=8*(l>>4)+e][n=l&15]
//   C/D: lane holds D[m=4*(l>>4)+j][n=l&15], j=0..3
__global__ __launch_bounds__(256) void proj_mfma(
    const float* __restrict__ X, const float* __restrict__ W,
    const float* __restrict__ bias, void* __restrict__ outp, const int mode)
{
    // [128 rows][32 k] bf16, row = 64B = 4 slots of 16B, slot XOR-swizzled.
    __shared__ __align__(16) unsigned short As[128 * 32];
    __shared__ __align__(16) unsigned short Bs[128 * 32];

    const int t  = threadIdx.x;
    const int l  = t & 63;
    const int w  = t >> 6;
    const int lr = l & 15;
    const int lg = l >> 4;
    const int wm = w >> 1;     // wave row 0..1
    const int wn = w & 1;      // wave col 0..1
    const int m0 = blockIdx.x * 128;
    const int n0 = blockIdx.y * 128;

    f32x4 acc[4][4];
#pragma unroll
    for (int mi = 0; mi < 4; mi++)
#pragma unroll
        for (int ni = 0; ni < 4; ni++) acc[mi][ni] = (f32x4){0.f, 0.f, 0.f, 0.f};

    const int fsw = (lr >> 1) & 3;   // fragment-read swizzle term

    for (int k0 = 0; k0 < D_; k0 += 32) {
        // ---- stage: 512 slot-units (row, slot_orig), 2 per thread ----
#pragma unroll
        for (int i = 0; i < 2; i++) {
            int v    = t + i * 256;        // 0..511
            int row  = v >> 2;             // 0..127
            int so   = v & 3;              // original slot = kk0/8
            const float* xp = X + (size_t)(m0 + row) * D_ + k0 + so * 8;
            float4 x0 = *(const float4*)(xp);
            float4 x1 = *(const float4*)(xp + 4);
            ushort4 pa, pb;
            pa.x = f2bf(x0.x); pa.y = f2bf(x0.y); pa.z = f2bf(x0.z); pa.w = f2bf(x0.w);
            pb.x = f2bf(x1.x); pb.y = f2bf(x1.y); pb.z = f2bf(x1.z); pb.w = f2bf(x1.w);
            int off = row * 32 + ((so ^ ((row >> 1) & 3)) << 3);
            *(ushort4*)&As[off]     = pa;
            *(ushort4*)&As[off + 4] = pb;

            const float* wp = W + (size_t)(n0 + row) * D_ + k0 + so * 8;
            float4 w0 = *(const float4*)(wp);
            float4 w1 = *(const float4*)(wp + 4);
            pa.x = f2bf(w0.x); pa.y = f2bf(w0.y); pa.z = f2bf(w0.z); pa.w = f2bf(w0.w);
            pb.x = f2bf(w1.x); pb.y = f2bf(w1.y); pb.z = f2bf(w1.z); pb.w = f2bf(w1.w);
            *(ushort4*)&Bs[off]     = pa;
            *(ushort4*)&Bs[off + 4] = pb;
        }
        __syncthreads();

        // ---- fragments (ds_read_b128, 2-way bank aliasing = free) ----
        bf16x8 af[4], bfr[4];
#pragma unroll
        for (int mi = 0; mi < 4; mi++) {
            int row = wm * 64 + mi * 16 + lr;
            af[mi] = *(const bf16x8*)&As[row * 32 + ((lg ^ fsw) << 3)];
        }
#pragma unroll
        for (int ni = 0; ni < 4; ni++) {
            int row = wn * 64 + ni * 16 + lr;
            bfr[ni] = *(const bf16x8*)&Bs[row * 32 + ((lg ^ fsw) << 3)];
        }
#pragma unroll
        for (int mi = 0; mi < 4; mi++)
#pragma unroll
            for (int ni = 0; ni < 4; ni++)
                acc[mi][ni] = __builtin_amdgcn_mfma_f32_16x16x32_bf16(
                    af[mi], bfr[ni], acc[mi][ni], 0, 0, 0);
        __syncthreads();
    }

    // ---- epilogue ----
    const int mrow0 = m0 + wm * 64;
    const int ncol0 = n0 + wn * 64;
    if (mode == 1) {
        float* out = (float*)outp;
#pragma unroll
        for (int mi = 0; mi < 4; mi++)
#pragma unroll
            for (int ni = 0; ni < 4; ni++) {
                int n = ncol0 + ni * 16 + lr;
                float bv = bias[n];
#pragma unroll
                for (int j = 0; j < 4; j++) {
                    int m = mrow0 + mi * 16 + 4 * lg + j;
                    out[(size_t)m * D_ + n] = acc[mi][ni][j] + bv;
                }
            }
    } else if (mode == 0) {
        unsigned short* out = (unsigned short*)outp;
#pragma unroll
        for (int mi = 0; mi < 4; mi++)
#pragma unroll
            for (int ni = 0; ni < 4; ni++) {
                int n = ncol0 + ni * 16 + lr;
                int h = n >> 6, dk = n & 63;
                float bv = bias[n];
#pragma unroll
                for (int j = 0; j < 4; j++) {
                    int m = mrow0 + mi * 16 + 4 * lg + j;
                    int b = m >> 11, s = m & (S_ - 1);
                    out[((size_t)(b * H_ + h) * S_ + s) * DK_ + dk] =
                        f2bf(acc[mi][ni][j] + bv);
                }
            }
    } else {
        // mode 2: V^T (B,H,DK,S) — the 4 j-rows are contiguous s -> ushort4
        unsigned short* out = (unsigned short*)outp;
#pragma unroll
        for (int mi = 0; mi < 4; mi++)
#pragma unroll
            for (int ni = 0; ni < 4; ni++) {
                int n = ncol0 + ni * 16 + lr;
                int h = n >> 6, dk = n & 63;
                float bv = bias[n];
                int m = mrow0 + mi * 16 + 4 * lg;    // j=0; s%4==0
                int b = m >> 11, s = m & (S_ - 1);
                ushort4 o;
                o.x = f2bf(acc[mi][ni][0] + bv);
                o.y = f2bf(acc[mi][ni][1] + bv);
                o.z = f2bf(acc[mi][ni][2] + bv);
                o.w = f2bf(acc[mi][ni][3] + bv);
                *(ushort4*)&out[((size_t)(b * H_ + h) * DK_ + dk) * S_ + s] = o;
            }
    }
}

// ---------------- MFMA flash attention (unchanged from R2) ----------------
__global__ __launch_bounds__(256) void attn_mfma(
    const unsigned short* __restrict__ Qb, const unsigned short* __restrict__ Kb,
    const unsigned short* __restrict__ VTb, const int* __restrict__ mask,
    float* __restrict__ O)
{
    __shared__ unsigned short Pt[4][1024];   // 16x64 bf16 per wave, swizzled

    const int t  = threadIdx.x;
    const int w  = t >> 6;
    const int l  = t & 63;
    const int lr = l & 15;
    const int lg = l >> 4;

    const int qt = blockIdx.x & 31;
    const int bh = blockIdx.x >> 5;
    const int b  = bh / H_;
    const int h  = bh - b * H_;
    const int q0 = qt * 64 + w * 16;

    const unsigned short* qp = Qb + ((size_t)bh * S_ + q0 + lr) * DK_ + lg * 8;
    bf16x8 aQ0 = *(const bf16x8*)(qp);
    bf16x8 aQ1 = *(const bf16x8*)(qp + 32);

    f32x4 acc_o[4];
    float m_i[4], l_i[4];
#pragma unroll
    for (int j = 0; j < 4; j++) {
        acc_o[j] = (f32x4){0.f, 0.f, 0.f, 0.f};
        m_i[j] = -INFINITY;
        l_i[j] = 0.f;
    }

    const unsigned short* kbase = Kb + (size_t)bh * S_ * DK_;
    const unsigned short* vbase = VTb + (size_t)bh * DK_ * S_;
    const int* mbase = mask + b * S_;
    unsigned short* pt = &Pt[w][0];

    for (int j0 = 0; j0 < S_; j0 += 64) {
        bf16x8 bK[4][2];
#pragma unroll
        for (int nf = 0; nf < 4; nf++) {
            const unsigned short* kp = kbase + (size_t)(j0 + nf * 16 + lr) * DK_ + lg * 8;
            bK[nf][0] = *(const bf16x8*)(kp);
            bK[nf][1] = *(const bf16x8*)(kp + 32);
        }
        int mv[4];
#pragma unroll
        for (int nf = 0; nf < 4; nf++) mv[nf] = mbase[j0 + nf * 16 + lr];

        f32x4 sc4[4];
#pragma unroll
        for (int nf = 0; nf < 4; nf++) {
            f32x4 z = (f32x4){0.f, 0.f, 0.f, 0.f};
            z = __builtin_amdgcn_mfma_f32_16x16x32_bf16(aQ0, bK[nf][0], z, 0, 0, 0);
            z = __builtin_amdgcn_mfma_f32_16x16x32_bf16(aQ1, bK[nf][1], z, 0, 0, 0);
            sc4[nf] = z;
        }

        bf16x8 bV[4][2];
#pragma unroll
        for (int nd = 0; nd < 4; nd++) {
            const unsigned short* vp = vbase + (size_t)(nd * 16 + lr) * S_ + j0 + lg * 8;
            bV[nd][0] = *(const bf16x8*)(vp);
            bV[nd][1] = *(const bf16x8*)(vp + 32);
        }

        float s[4][4];
#pragma unroll
        for (int nf = 0; nf < 4; nf++) {
            bool msk = (mv[nf] == 0);
#pragma unroll
            for (int j = 0; j < 4; j++)
                s[nf][j] = msk ? -1e9f : sc4[nf][j] * 0.125f;
        }

        float pr[4][4], scale_j[4];
#pragma unroll
        for (int j = 0; j < 4; j++) {
            float rm = fmaxf(fmaxf(s[0][j], s[1][j]), fmaxf(s[2][j], s[3][j]));
            rm = fmaxf(rm, __shfl_xor(rm, 1));
            rm = fmaxf(rm, __shfl_xor(rm, 2));
            rm = fmaxf(rm, __shfl_xor(rm, 4));
            rm = fmaxf(rm, __shfl_xor(rm, 8));
            float mn = fmaxf(m_i[j], rm);
            float sc = __expf(m_i[j] - mn);
            float rs = 0.f;
#pragma unroll
            for (int nf = 0; nf < 4; nf++) { pr[nf][j] = __expf(s[nf][j] - mn); rs += pr[nf][j]; }
            rs += __shfl_xor(rs, 1);
            rs += __shfl_xor(rs, 2);
            rs += __shfl_xor(rs, 4);
            rs += __shfl_xor(rs, 8);
            l_i[j] = l_i[j] * sc + rs;
            m_i[j] = mn;
            scale_j[j] = sc;
        }

#pragma unroll
        for (int nd = 0; nd < 4; nd++)
#pragma unroll
            for (int j = 0; j < 4; j++) acc_o[nd][j] *= scale_j[j];

#pragma unroll
        for (int nf = 0; nf < 4; nf++)
#pragma unroll
            for (int j = 0; j < 4; j++) {
                int m = lg * 4 + j;
                int n = nf * 16 + lr;
                pt[(m * 64 + n) ^ ((m & 7) << 3)] = f2bf(pr[nf][j]);
            }
        int i0 = (lr * 64 + lg * 8) ^ ((lr & 7) << 3);
        int i1 = (lr * 64 + 32 + lg * 8) ^ ((lr & 7) << 3);
        bf16x8 aP0 = *(const bf16x8*)&pt[i0];
        bf16x8 aP1 = *(const bf16x8*)&pt[i1];

#pragma unroll
        for (int nd = 0; nd < 4; nd++) {
            acc_o[nd] = __builtin_amdgcn_mfma_f32_16x16x32_bf16(aP0, bV[nd][0], acc_o[nd], 0, 0, 0);
            acc_o[nd] = __builtin_amdgcn_mfma_f32_16x16x32_bf16(aP1, bV[nd][1], acc_o[nd], 0, 0, 0);
        }
    }

    float* ob = O + ((size_t)b * S_ + q0) * D_ + h * DK_;
#pragma unroll
    for (int j = 0; j < 4; j++) {
        float inv = 1.f / l_i[j];
        int m = lg * 4 + j;
#pragma unroll
        for (int nd = 0; nd < 4; nd++)
            ob[(size_t)m * D_ + nd * 16 + lr] = acc_o[nd][j] * inv;
    }
}

// ---------------- host launcher ----------------
extern "C" void kernel_launch(void* const* d_in, const int* in_sizes, int n_in,
                              void* d_out, int out_size, void* d_ws, size_t ws_size,
                              hipStream_t stream) {
    (void)in_sizes; (void)n_in; (void)out_size; (void)ws_size;

    const float* query = (const float*)d_in[0];
    const float* key_  = (const float*)d_in[1];
    const float* value = (const float*)d_in[2];
    const int*   mask  = (const int*)d_in[3];
    const float* Wq = (const float*)d_in[4];  const float* bq = (const float*)d_in[5];
    const float* Wk = (const float*)d_in[6];  const float* bk = (const float*)d_in[7];
    const float* Wv = (const float*)d_in[8];  const float* bv = (const float*)d_in[9];
    const float* Wo = (const float*)d_in[10]; const float* bo = (const float*)d_in[11];
    float* out = (float*)d_out;

    // Workspace: Qb,Kb (B,H,S,DK) bf16; VT (B,H,DK,S) bf16; Xb (B,S,D) fp32.
    unsigned short* Qb = (unsigned short*)d_ws;
    unsigned short* Kb = Qb + (size_t)M_ * D_;
    unsigned short* VT = Kb + (size_t)M_ * D_;
    float*          Xb = (float*)(VT + (size_t)M_ * D_);

    dim3 gproj(M_ / 128, D_ / 128);   // 64 x 6
    proj_mfma<<<gproj, 256, 0, stream>>>(query, Wq, bq, Qb, 0);
    proj_mfma<<<gproj, 256, 0, stream>>>(key_,  Wk, bk, Kb, 0);
    proj_mfma<<<gproj, 256, 0, stream>>>(value, Wv, bv, VT, 2);

    attn_mfma<<<dim3(B_ * H_ * (S_ / 64)), 256, 0, stream>>>(Qb, Kb, VT, mask, Xb);

    proj_mfma<<<gproj, 256, 0, stream>>>(Xb, Wo, bo, (void*)out, 1);
}